// Round 1
// baseline (407.700 us; speedup 1.0000x reference)
//
#include <hip/hip_runtime.h>

constexpr int IN_F  = 32;
constexpr int OUT_F = 128;
constexpr int BLOCK = 256;
constexpr int RPT   = 2;   // rows per thread

__global__ __launch_bounds__(BLOCK)
void rbf_kernel(const float* __restrict__ x,
                const float* __restrict__ centres,
                const float* __restrict__ log_sigmas,
                float* __restrict__ out)
{
    __shared__ float ct[IN_F][OUT_F];   // ct[k][o] = centres[o][k]
    __shared__ float c2s[OUT_F];
    __shared__ float ivs[OUT_F];

    const int tid = threadIdx.x;

    // ---- load this thread's x rows into registers (independent of LDS) ----
    const long long rowBase = (long long)blockIdx.x * (BLOCK * RPT) + tid;
    float xv[RPT][IN_F];
    float x2[RPT];
    #pragma unroll
    for (int r = 0; r < RPT; ++r) {
        const float* xr = x + (rowBase + (long long)r * BLOCK) * IN_F;
        float s = 0.f;
        #pragma unroll
        for (int kc = 0; kc < IN_F / 4; ++kc) {
            const float4 v = *reinterpret_cast<const float4*>(xr + kc * 4);
            xv[r][kc*4+0] = v.x; xv[r][kc*4+1] = v.y;
            xv[r][kc*4+2] = v.z; xv[r][kc*4+3] = v.w;
            s = fmaf(v.x, v.x, s); s = fmaf(v.y, v.y, s);
            s = fmaf(v.z, v.z, s); s = fmaf(v.w, v.w, s);
        }
        x2[r] = s;
    }

    // ---- stage transposed centres + c2 + inv_var into LDS (once/block) ----
    if (tid < OUT_F) {
        const int o = tid;
        float c2 = 0.f;
        #pragma unroll
        for (int kc = 0; kc < IN_F / 4; ++kc) {
            const float4 c4 = *reinterpret_cast<const float4*>(centres + o * IN_F + kc * 4);
            ct[kc*4+0][o] = c4.x; ct[kc*4+1][o] = c4.y;
            ct[kc*4+2][o] = c4.z; ct[kc*4+3][o] = c4.w;
            c2 = fmaf(c4.x, c4.x, c2); c2 = fmaf(c4.y, c4.y, c2);
            c2 = fmaf(c4.z, c4.z, c2); c2 = fmaf(c4.w, c4.w, c2);
        }
        c2s[o] = c2;
        ivs[o] = __expf(-2.0f * log_sigmas[o]);
    }
    __syncthreads();

    // ---- main loop: 4 outputs per iteration, broadcast centre reads ----
    #pragma unroll 1
    for (int ob = 0; ob < OUT_F; ob += 4) {
        float acc[RPT][4];
        #pragma unroll
        for (int r = 0; r < RPT; ++r) {
            acc[r][0] = 0.f; acc[r][1] = 0.f; acc[r][2] = 0.f; acc[r][3] = 0.f;
        }

        #pragma unroll
        for (int k = 0; k < IN_F; ++k) {
            const float4 c4 = *reinterpret_cast<const float4*>(&ct[k][ob]);
            #pragma unroll
            for (int r = 0; r < RPT; ++r) {
                const float xk = xv[r][k];
                acc[r][0] = fmaf(xk, c4.x, acc[r][0]);
                acc[r][1] = fmaf(xk, c4.y, acc[r][1]);
                acc[r][2] = fmaf(xk, c4.z, acc[r][2]);
                acc[r][3] = fmaf(xk, c4.w, acc[r][3]);
            }
        }

        const float4 c2_4 = *reinterpret_cast<const float4*>(&c2s[ob]);
        const float4 iv4  = *reinterpret_cast<const float4*>(&ivs[ob]);
        #pragma unroll
        for (int r = 0; r < RPT; ++r) {
            float4 o4;
            float t;
            t = fmaxf(fmaf(-2.f, acc[r][0], x2[r] + c2_4.x), 0.f); o4.x = __expf(-t * iv4.x);
            t = fmaxf(fmaf(-2.f, acc[r][1], x2[r] + c2_4.y), 0.f); o4.y = __expf(-t * iv4.y);
            t = fmaxf(fmaf(-2.f, acc[r][2], x2[r] + c2_4.z), 0.f); o4.z = __expf(-t * iv4.z);
            t = fmaxf(fmaf(-2.f, acc[r][3], x2[r] + c2_4.w), 0.f); o4.w = __expf(-t * iv4.w);
            *reinterpret_cast<float4*>(out + (rowBase + (long long)r * BLOCK) * OUT_F + ob) = o4;
        }
    }
}

extern "C" void kernel_launch(void* const* d_in, const int* in_sizes, int n_in,
                              void* d_out, int out_size, void* d_ws, size_t ws_size,
                              hipStream_t stream) {
    const float* x          = (const float*)d_in[0];
    const float* centres    = (const float*)d_in[1];
    const float* log_sigmas = (const float*)d_in[2];
    float* out = (float*)d_out;

    const int n = in_sizes[0] / IN_F;          // 1048576 rows
    const int blocks = n / (BLOCK * RPT);      // 2048 blocks (exact)
    rbf_kernel<<<blocks, BLOCK, 0, stream>>>(x, centres, log_sigmas, out);
}

// Round 2
// 154.274 us; speedup vs baseline: 2.6427x; 2.6427x over previous
//
#include <hip/hip_runtime.h>

constexpr int IN_F  = 32;
constexpr int OUT_F = 128;
constexpr int BLOCK = 256;
constexpr int WAVES = BLOCK / 64;
constexpr int RSTAGE = 8;          // rows staged per wave per iteration

using f32x2 = __attribute__((ext_vector_type(2))) float;

__global__ __launch_bounds__(BLOCK)
void rbf_kernel(const float* __restrict__ x,
                const float* __restrict__ centres,
                const float* __restrict__ log_sigmas,
                float* __restrict__ out,
                int rows_per_wave)
{
    __shared__ float4 xs[WAVES][RSTAGE][IN_F / 4];
    __shared__ float  x2s[WAVES][RSTAGE];

    const int tid  = threadIdx.x;
    const int wv   = tid >> 6;
    const int lane = tid & 63;

    // ---- per-lane centres (outputs 2*lane, 2*lane+1) into registers ----
    const int o0 = lane * 2;
    float c0[IN_F], c1[IN_F];
    float c2a = 0.f, c2b = 0.f;
    #pragma unroll
    for (int kc = 0; kc < IN_F / 4; ++kc) {
        const float4 a = *reinterpret_cast<const float4*>(centres + (size_t)(o0 + 0) * IN_F + kc * 4);
        const float4 b = *reinterpret_cast<const float4*>(centres + (size_t)(o0 + 1) * IN_F + kc * 4);
        c0[kc*4+0] = a.x; c0[kc*4+1] = a.y; c0[kc*4+2] = a.z; c0[kc*4+3] = a.w;
        c1[kc*4+0] = b.x; c1[kc*4+1] = b.y; c1[kc*4+2] = b.z; c1[kc*4+3] = b.w;
        c2a = fmaf(a.x,a.x,c2a); c2a = fmaf(a.y,a.y,c2a);
        c2a = fmaf(a.z,a.z,c2a); c2a = fmaf(a.w,a.w,c2a);
        c2b = fmaf(b.x,b.x,c2b); c2b = fmaf(b.y,b.y,c2b);
        c2b = fmaf(b.z,b.z,c2b); c2b = fmaf(b.w,b.w,c2b);
    }
    const float iv0 = __expf(-2.0f * log_sigmas[o0 + 0]);
    const float iv1 = __expf(-2.0f * log_sigmas[o0 + 1]);

    const size_t waveRow0 = ((size_t)blockIdx.x * WAVES + wv) * (size_t)rows_per_wave;
    const int rs = lane >> 3;      // row within stage this lane helps load
    const int q  = lane & 7;       // float4 slot within that row

    for (int it = 0; it < rows_per_wave; it += RSTAGE) {
        // ---- stage 8 rows: one coalesced 1 KB load per wave ----
        const float4 v = *reinterpret_cast<const float4*>(
            x + (waveRow0 + it) * IN_F + lane * 4);
        float s;
        s = v.x * v.x;
        s = fmaf(v.y, v.y, s);
        s = fmaf(v.z, v.z, s);
        s = fmaf(v.w, v.w, s);
        s += __shfl_xor(s, 1);
        s += __shfl_xor(s, 2);
        s += __shfl_xor(s, 4);     // lanes sharing rs now hold full ||x||^2
        xs[wv][rs][q] = v;
        if (q == 0) x2s[wv][rs] = s;
        __syncthreads();           // within-wave LDS write->read ordering

        #pragma unroll
        for (int rr = 0; rr < RSTAGE; ++rr) {
            float acc0 = 0.f, acc1 = 0.f;
            #pragma unroll
            for (int kc = 0; kc < IN_F / 4; ++kc) {
                const float4 xk = xs[wv][rr][kc];   // wave-uniform: broadcast
                acc0 = fmaf(xk.x, c0[kc*4+0], acc0);
                acc0 = fmaf(xk.y, c0[kc*4+1], acc0);
                acc0 = fmaf(xk.z, c0[kc*4+2], acc0);
                acc0 = fmaf(xk.w, c0[kc*4+3], acc0);
                acc1 = fmaf(xk.x, c1[kc*4+0], acc1);
                acc1 = fmaf(xk.y, c1[kc*4+1], acc1);
                acc1 = fmaf(xk.z, c1[kc*4+2], acc1);
                acc1 = fmaf(xk.w, c1[kc*4+3], acc1);
            }
            const float x2 = x2s[wv][rr];
            const float t0 = fmaxf(fmaf(-2.0f, acc0, x2 + c2a), 0.0f);
            const float t1 = fmaxf(fmaf(-2.0f, acc1, x2 + c2b), 0.0f);
            f32x2 o;
            o.x = __expf(-t0 * iv0);
            o.y = __expf(-t1 * iv1);
            // lane l writes bytes [8l, 8l+8) of this row: 512 B contiguous/wave
            __builtin_nontemporal_store(o,
                reinterpret_cast<f32x2*>(out + (waveRow0 + it + rr) * OUT_F + o0));
        }
        __syncthreads();           // protect xs before next stage overwrites
    }
}

extern "C" void kernel_launch(void* const* d_in, const int* in_sizes, int n_in,
                              void* d_out, int out_size, void* d_ws, size_t ws_size,
                              hipStream_t stream) {
    const float* x          = (const float*)d_in[0];
    const float* centres    = (const float*)d_in[1];
    const float* log_sigmas = (const float*)d_in[2];
    float* out = (float*)d_out;

    const int n = in_sizes[0] / IN_F;              // 1,048,576 rows
    const int blocks = 2048;
    const int rows_per_block = n / blocks;         // 512
    const int rows_per_wave  = rows_per_block / WAVES;  // 128
    rbf_kernel<<<blocks, BLOCK, 0, stream>>>(x, centres, log_sigmas, out, rows_per_wave);
}